// Round 13
// baseline (109.264 us; speedup 1.0000x reference)
//
#include <hip/hip_runtime.h>

// B=32, L=512, D=1024; 7 linear experts + identity, routed per token.
// 3 launches:
//  K1 routeconv_k: block 0 = route (count/prefix/table/slot scatter, both
//     linear slots [0,nlin) and identity list [nlin,16384) in ctok);
//     blocks 1..1792 = W f32->bf16 convert. Independent -> no race.
//  K2 identity_k: one wave per identity token, f32 row copy.
//  K3 gemm_k: 256 blocks (1/CU), 256x256 tile, 8 waves (2Mx4N), BK=64,
//     XOR-swizzled LDS, distinct-array dbuf, R9's proven tile order.
//     A is gathered DIRECTLY from raw f32 actions (no Abf round-trip):
//     f32 loads issued with B gloads, cvt+ds_write after MFMA2 (T14).

#define NTOK 16384
#define DDIM 1024
#define NEXP 7
#define BM 256
#define BN 256
#define BK 64
#define NKT (DDIM / BK)

// ws ints
#define WI_OFFS   16          // [8]; offs[7] = nlin
#define WI_NTILES 32
#define WI_TABLE  64          // [72][2] {expert, crow0}
#define WI_CTOK   512         // [16384]: [0,nlin) slot->token; [nlin,..) identity
#define WS_WBF_B  1048576     // 14 MB bf16 W

typedef __attribute__((ext_vector_type(8))) short short8;
typedef __attribute__((ext_vector_type(4))) float f32x4;

__device__ __forceinline__ unsigned short f2bf(float f) {
    unsigned u = __float_as_uint(f);
    u += 0x7fff + ((u >> 16) & 1);
    return (unsigned short)(u >> 16);
}

__device__ __forceinline__ void gload16(const void* g, void* l) {
    __builtin_amdgcn_global_load_lds(
        (const __attribute__((address_space(1))) void*)g,
        (__attribute__((address_space(3))) void*)l, 16, 0, 0);
}

// block 0: route (2-pass: count hist -> prefix/table -> scatter).
// blocks 1..1792: W f32->bf16.
__global__ __launch_bounds__(256) void routeconv_k(
    const int* __restrict__ type, int* __restrict__ wsi,
    const float* __restrict__ W, unsigned short* __restrict__ Wbf) {
    const int bid = blockIdx.x, tid = threadIdx.x;
    if (bid == 0) {
        __shared__ int h[4][8];
        __shared__ int base2[4][8];
        const int wave = tid >> 6;
        if (tid < 32) ((int*)h)[tid] = 0;
        __syncthreads();
        for (int i = 0; i < 64; ++i) {
            int k = type[i * 256 + tid];
            atomicAdd(&h[wave][k], 1);
        }
        __syncthreads();
        if (tid == 0) {
            int acc = 0, t = 0;
            for (int e = 0; e < NEXP; ++e) {
                wsi[WI_OFFS + e] = acc;
                int run = acc;
                for (int w = 0; w < 4; ++w) { base2[w][e + 1] = run; run += h[w][e + 1]; }
                int nt = (run - acc + BM - 1) >> 8;
                for (int i = 0; i < nt; ++i) {
                    wsi[WI_TABLE + 2 * t] = e;
                    wsi[WI_TABLE + 2 * t + 1] = acc + i * BM;
                    ++t;
                }
                acc = run;
            }
            wsi[WI_OFFS + NEXP] = acc;
            wsi[WI_NTILES] = t;
            int run = acc;                       // identity list after linear
            for (int w = 0; w < 4; ++w) { base2[w][0] = run; run += h[w][0]; }
        }
        __syncthreads();
        if (tid < 32) ((int*)h)[tid] = 0;
        __syncthreads();
        for (int i = 0; i < 64; ++i) {
            int t2 = i * 256 + tid;
            int k = type[t2];
            int pos = base2[wave][k] + atomicAdd(&h[wave][k], 1);
            wsi[WI_CTOK + pos] = t2;
        }
    } else {
        size_t i = ((size_t)(bid - 1) * 256 + tid) * 16;
        const float4* src = (const float4*)(W + i);
        float4 v0 = src[0], v1 = src[1], v2 = src[2], v3 = src[3];
        short8 h0, h1;
        h0[0]=f2bf(v0.x); h0[1]=f2bf(v0.y); h0[2]=f2bf(v0.z); h0[3]=f2bf(v0.w);
        h0[4]=f2bf(v1.x); h0[5]=f2bf(v1.y); h0[6]=f2bf(v1.z); h0[7]=f2bf(v1.w);
        h1[0]=f2bf(v2.x); h1[1]=f2bf(v2.y); h1[2]=f2bf(v2.z); h1[3]=f2bf(v2.w);
        h1[4]=f2bf(v3.x); h1[5]=f2bf(v3.y); h1[6]=f2bf(v3.z); h1[7]=f2bf(v3.w);
        *(short8*)(Wbf + i) = h0;
        *(short8*)(Wbf + i + 8) = h1;
    }
}

// One wave per identity token: f32 row copy A -> out.
__global__ __launch_bounds__(256) void identity_k(
    const float* __restrict__ A, const int* __restrict__ wsi,
    float* __restrict__ out) {
    const int wave = threadIdx.x >> 6, lane = threadIdx.x & 63;
    const int nlin = wsi[WI_OFFS + NEXP];
    const int idx = blockIdx.x * 4 + wave;
    if (idx >= NTOK - nlin) return;
    const int tok = wsi[WI_CTOK + nlin + idx];
    const float4* s = (const float4*)(A + (size_t)tok * DDIM);
    float4* d = (float4*)(out + (size_t)tok * DDIM);
#pragma unroll
    for (int j = 0; j < 4; ++j) d[lane + j * 64] = s[lane + j * 64];
}

// One K-tile, R9's proven order: reads1 -> stage-issue (B gloads + A f32
// loads) -> MFMA1 -> reads2 -> MFMA2 -> vmcnt(0) -> cvt+ds_write A -> bar.
#define TILE(Abase, Bbase, dNA, sNB, KT)                           \
    do {                                                           \
        short8 a1[8], b1[4];                                       \
        float4 fA[8];                                              \
        _Pragma("unroll")                                          \
        for (int m = 0; m < 8; ++m)                                \
            a1[m] = *(const short8*)(Abase + sl0 + m * 2048);      \
        _Pragma("unroll")                                          \
        for (int n = 0; n < 4; ++n)                                \
            b1[n] = *(const short8*)(Bbase + sl0 + n * 2048);      \
        if ((KT) + 1 < NKT) {                                      \
            const int ke_ = ((KT) + 1) * BK;                       \
            _Pragma("unroll")                                      \
            for (int q = 0; q < 4; ++q)                            \
                gload16(bSrc[q] + ke_, sNB + q * 8192);            \
            _Pragma("unroll")                                      \
            for (int q = 0; q < 4; ++q) {                          \
                const float* p = aSrcF[q] + ke_;                   \
                fA[2 * q]     = *(const float4*)p;                 \
                fA[2 * q + 1] = *(const float4*)(p + 4);           \
            }                                                      \
        }                                                          \
        __builtin_amdgcn_s_setprio(1);                             \
        _Pragma("unroll")                                          \
        for (int m = 0; m < 8; ++m)                                \
            _Pragma("unroll")                                      \
            for (int n = 0; n < 4; ++n)                            \
                acc[m][n] = __builtin_amdgcn_mfma_f32_16x16x32_bf16(\
                    a1[m], b1[n], acc[m][n], 0, 0, 0);             \
        __builtin_amdgcn_s_setprio(0);                             \
        short8 a2[8], b2[4];                                       \
        _Pragma("unroll")                                          \
        for (int m = 0; m < 8; ++m)                                \
            a2[m] = *(const short8*)(Abase + sl1 + m * 2048);      \
        _Pragma("unroll")                                          \
        for (int n = 0; n < 4; ++n)                                \
            b2[n] = *(const short8*)(Bbase + sl1 + n * 2048);      \
        __builtin_amdgcn_s_setprio(1);                             \
        _Pragma("unroll")                                          \
        for (int m = 0; m < 8; ++m)                                \
            _Pragma("unroll")                                      \
            for (int n = 0; n < 4; ++n)                            \
                acc[m][n] = __builtin_amdgcn_mfma_f32_16x16x32_bf16(\
                    a2[m], b2[n], acc[m][n], 0, 0, 0);             \
        __builtin_amdgcn_s_setprio(0);                             \
        asm volatile("s_waitcnt vmcnt(0)" ::: "memory");           \
        if ((KT) + 1 < NKT) {                                      \
            _Pragma("unroll")                                      \
            for (int q = 0; q < 4; ++q) {                          \
                short8 w;                                          \
                w[0]=f2bf(fA[2*q].x);   w[1]=f2bf(fA[2*q].y);      \
                w[2]=f2bf(fA[2*q].z);   w[3]=f2bf(fA[2*q].w);      \
                w[4]=f2bf(fA[2*q+1].x); w[5]=f2bf(fA[2*q+1].y);    \
                w[6]=f2bf(fA[2*q+1].z); w[7]=f2bf(fA[2*q+1].w);    \
                *(short8*)(dNA + awOff[q]) = w;                    \
            }                                                      \
        }                                                          \
        __builtin_amdgcn_s_barrier();                              \
    } while (0)

__global__ __launch_bounds__(512, 2) void gemm_k(
    const float* __restrict__ Araw,
    const unsigned short* __restrict__ Wbf,
    const float* __restrict__ bias, float* __restrict__ out,
    const int* __restrict__ wsi) {
    const int bid = blockIdx.x;              // 0..255, 1 per CU
    const int c = bid & 7;                   // XCD
    const int g = bid >> 3;
    const int ntiles = wsi[WI_NTILES];
    const int* offs = wsi + WI_OFFS;
    const int* tab  = wsi + WI_TABLE;
    const int* ctok = wsi + WI_CTOK;

    __shared__ unsigned short As0[BM * BK];   // 32 KB each, distinct dbuf
    __shared__ unsigned short As1[BM * BK];
    __shared__ unsigned short Bs0[BM * BK];
    __shared__ unsigned short Bs1[BM * BK];

    const int tid = threadIdx.x, lane = tid & 63, wave = tid >> 6;
    const int wr = wave >> 2, wc = wave & 3;     // wave-tile 128x64
    const int lane15 = lane & 15;
    const int srow = lane >> 3;                          // 0..7
    const int schunk = ((lane & 7) ^ srow) * 8;          // inverse-swz (B src)

    const int sl0 = (((lane >> 4)) ^ (lane & 7)) * 16;
    const int sl1 = ((4 | (lane >> 4)) ^ (lane & 7)) * 16;
    const char* aR0 = (const char*)As0 + wr * 16384 + lane15 * 128;
    const char* aR1 = (const char*)As1 + wr * 16384 + lane15 * 128;
    const char* bR0 = (const char*)Bs0 + wc * 8192 + lane15 * 128;
    const char* bR1 = (const char*)Bs1 + wc * 8192 + lane15 * 128;
    char* sB0 = (char*)Bs0 + wave * 1024;
    char* sB1 = (char*)Bs1 + wave * 1024;

    // A reg-stage: lane covers row q*64+wave*8+srow, chunk (lane&7);
    // ds_write slot = chunk ^ (row&7) = (lane&7) ^ (srow&7).
    int awOff[4];
#pragma unroll
    for (int q = 0; q < 4; ++q)
        awOff[q] = (q * 64 + wave * 8 + srow) * 128 +
                   (((lane & 7) ^ (srow & 7)) * 16);

    for (int rep = 0; rep < 2; ++rep) {
        const int q4 = g + 32 * rep;
        const int ty = (q4 >> 2) * 8 + c;
        const int tx = q4 & 3;
        if (ty >= ntiles) break;

        const int e     = tab[2 * ty];
        const int crow0 = tab[2 * ty + 1];
        const int nend  = offs[e + 1];
        const int col0  = tx * BN;
        const unsigned short* Wb = Wbf + (size_t)e * DDIM * DDIM;

        const float* aSrcF[4];
        const unsigned short* bSrc[4];
#pragma unroll
        for (int q = 0; q < 4; ++q) {
            int r = min(crow0 + q * 64 + wave * 8 + srow, NTOK - 1);
            aSrcF[q] = Araw + (size_t)ctok[r] * DDIM + (lane & 7) * 8;
            bSrc[q] = Wb + (size_t)(col0 + q * 64 + wave * 8 + srow) * DDIM + schunk;
        }

        f32x4 acc[8][4];
#pragma unroll
        for (int m = 0; m < 8; ++m)
#pragma unroll
            for (int n = 0; n < 4; ++n) acc[m][n] = (f32x4){0.f, 0.f, 0.f, 0.f};

        // prologue: stage K-tile 0 into buf 0
        {
#pragma unroll
            for (int q = 0; q < 4; ++q) gload16(bSrc[q], sB0 + q * 8192);
            float4 fA[8];
#pragma unroll
            for (int q = 0; q < 4; ++q) {
                fA[2 * q]     = *(const float4*)aSrcF[q];
                fA[2 * q + 1] = *(const float4*)(aSrcF[q] + 4);
            }
            asm volatile("s_waitcnt vmcnt(0)" ::: "memory");
#pragma unroll
            for (int q = 0; q < 4; ++q) {
                short8 w;
                w[0]=f2bf(fA[2*q].x);   w[1]=f2bf(fA[2*q].y);
                w[2]=f2bf(fA[2*q].z);   w[3]=f2bf(fA[2*q].w);
                w[4]=f2bf(fA[2*q+1].x); w[5]=f2bf(fA[2*q+1].y);
                w[6]=f2bf(fA[2*q+1].z); w[7]=f2bf(fA[2*q+1].w);
                *(short8*)((char*)As0 + awOff[q]) = w;
            }
            __builtin_amdgcn_s_barrier();
        }

        for (int kt2 = 0; kt2 < NKT / 2; ++kt2) {
            TILE(aR0, bR0, (char*)As1, sB1, 2 * kt2);
            TILE(aR1, bR1, (char*)As0, sB0, 2 * kt2 + 1);
        }

        // epilogue: bias + gathered store (C/D: col=lane&15, row=(lane>>4)*4+r)
        const int crow4 = (lane >> 4) * 4;
        float bv[4];
#pragma unroll
        for (int n = 0; n < 4; ++n)
            bv[n] = bias[e * DDIM + col0 + wc * 64 + n * 16 + lane15];

#pragma unroll
        for (int m = 0; m < 8; ++m) {
#pragma unroll
            for (int r = 0; r < 4; ++r) {
                int gr = crow0 + wr * 128 + m * 16 + crow4 + r;
                if (gr >= nend) continue;
                int tok = ctok[gr];
                float* orow = out + (size_t)tok * DDIM + col0 + wc * 64 + lane15;
#pragma unroll
                for (int n = 0; n < 4; ++n)
                    orow[n * 16] = acc[m][n][r] + bv[n];
            }
        }
        __builtin_amdgcn_s_barrier();   // LDS quiesced before next rep's stage
    }
}

extern "C" void kernel_launch(void* const* d_in, const int* in_sizes, int n_in,
                              void* d_out, int out_size, void* d_ws, size_t ws_size,
                              hipStream_t stream) {
    const float* actions = (const float*)d_in[0];
    const int*   atype   = (const int*)d_in[1];
    const float* W       = (const float*)d_in[2];
    const float* bias    = (const float*)d_in[3];
    float* out = (float*)d_out;

    int* wsi = (int*)d_ws;
    unsigned short* Wbf = (unsigned short*)((char*)d_ws + WS_WBF_B);

    routeconv_k<<<1 + 1792, 256, 0, stream>>>(atype, wsi, W, Wbf);
    identity_k<<<NTOK / 4, 256, 0, stream>>>(actions, wsi, out);
    gemm_k<<<256, 512, 0, stream>>>(actions, Wbf, bias, out, wsi);
}

// Round 14
// 91.823 us; speedup vs baseline: 1.1899x; 1.1899x over previous
//
#include <hip/hip_runtime.h>

// B=32, L=512, D=1024; 7 linear experts + identity, routed per token.
// 3 launches:
//  K1 routeconv_k: block 0 = route (2-pass hist/prefix/table/scatter);
//     blocks 1..1792 = W f32->bf16.
//  K2 aconv_k: slot s -> gather+convert A row to Abf[s] (linear) or
//     identity row copy to out.
//  K3 gemm_k: 256 blocks (1/CU), 256x256 tile, 8 waves (2Mx4N), BK=64,
//     XOR-swizzled LDS, A double-buffer + B TRIPLE-buffer (160KB exact),
//     counted vmcnt(4): B(t+2) stays in flight ACROSS the tile barrier
//     (T4), fully unrolled 16-tile loop, R9's proven intra-tile order.

#define NTOK 16384
#define DDIM 1024
#define NEXP 7
#define BM 256
#define BN 256
#define BK 64
#define NKT (DDIM / BK)

// ws ints / byte offsets
#define WI_OFFS   16          // [8]; offs[7] = nlin
#define WI_NTILES 32
#define WI_TABLE  64          // [72][2] {expert, crow0}
#define WI_CTOK   512         // [16384]: [0,nlin) slot->token; rest identity
#define WS_ABF_B  1048576                       // 32 MB bf16 A (compact)
#define WS_WBF_B  (WS_ABF_B + NTOK * DDIM * 2)  // 14 MB bf16 W

typedef __attribute__((ext_vector_type(8))) short short8;
typedef __attribute__((ext_vector_type(4))) float f32x4;

__device__ __forceinline__ unsigned short f2bf(float f) {
    unsigned u = __float_as_uint(f);
    u += 0x7fff + ((u >> 16) & 1);
    return (unsigned short)(u >> 16);
}

__device__ __forceinline__ void gload16(const void* g, void* l) {
    __builtin_amdgcn_global_load_lds(
        (const __attribute__((address_space(1))) void*)g,
        (__attribute__((address_space(3))) void*)l, 16, 0, 0);
}

// block 0: route (2-pass). blocks 1..1792: W f32->bf16.
__global__ __launch_bounds__(256) void routeconv_k(
    const int* __restrict__ type, int* __restrict__ wsi,
    const float* __restrict__ W, unsigned short* __restrict__ Wbf) {
    const int bid = blockIdx.x, tid = threadIdx.x;
    if (bid == 0) {
        __shared__ int h[4][8];
        __shared__ int base2[4][8];
        const int wave = tid >> 6;
        if (tid < 32) ((int*)h)[tid] = 0;
        __syncthreads();
        for (int i = 0; i < 64; ++i) {
            int k = type[i * 256 + tid];
            atomicAdd(&h[wave][k], 1);
        }
        __syncthreads();
        if (tid == 0) {
            int acc = 0, t = 0;
            for (int e = 0; e < NEXP; ++e) {
                wsi[WI_OFFS + e] = acc;
                int run = acc;
                for (int w = 0; w < 4; ++w) { base2[w][e + 1] = run; run += h[w][e + 1]; }
                int nt = (run - acc + BM - 1) >> 8;
                for (int i = 0; i < nt; ++i) {
                    wsi[WI_TABLE + 2 * t] = e;
                    wsi[WI_TABLE + 2 * t + 1] = acc + i * BM;
                    ++t;
                }
                acc = run;
            }
            wsi[WI_OFFS + NEXP] = acc;
            wsi[WI_NTILES] = t;
            int run = acc;                       // identity list after linear
            for (int w = 0; w < 4; ++w) { base2[w][0] = run; run += h[w][0]; }
        }
        __syncthreads();
        if (tid < 32) ((int*)h)[tid] = 0;
        __syncthreads();
        for (int i = 0; i < 64; ++i) {
            int t2 = i * 256 + tid;
            int k = type[t2];
            int pos = base2[wave][k] + atomicAdd(&h[wave][k], 1);
            wsi[WI_CTOK + pos] = t2;
        }
    } else {
        size_t i = ((size_t)(bid - 1) * 256 + tid) * 16;
        const float4* src = (const float4*)(W + i);
        float4 v0 = src[0], v1 = src[1], v2 = src[2], v3 = src[3];
        short8 h0, h1;
        h0[0]=f2bf(v0.x); h0[1]=f2bf(v0.y); h0[2]=f2bf(v0.z); h0[3]=f2bf(v0.w);
        h0[4]=f2bf(v1.x); h0[5]=f2bf(v1.y); h0[6]=f2bf(v1.z); h0[7]=f2bf(v1.w);
        h1[0]=f2bf(v2.x); h1[1]=f2bf(v2.y); h1[2]=f2bf(v2.z); h1[3]=f2bf(v2.w);
        h1[4]=f2bf(v3.x); h1[5]=f2bf(v3.y); h1[6]=f2bf(v3.z); h1[7]=f2bf(v3.w);
        *(short8*)(Wbf + i) = h0;
        *(short8*)(Wbf + i + 8) = h1;
    }
}

// One wave per slot: linear -> gather+convert to Abf[s]; identity -> copy.
__global__ __launch_bounds__(256) void aconv_k(
    const float* __restrict__ A, const int* __restrict__ wsi,
    unsigned short* __restrict__ Abf, float* __restrict__ out) {
    const int wave = threadIdx.x >> 6, lane = threadIdx.x & 63;
    const int s = blockIdx.x * 4 + wave;
    const int nlin = wsi[WI_OFFS + NEXP];
    const int tok = wsi[WI_CTOK + s];
    const float4* src = (const float4*)(A + (size_t)tok * DDIM);
    if (s >= nlin) {
        float4* d = (float4*)(out + (size_t)tok * DDIM);
#pragma unroll
        for (int j = 0; j < 4; ++j) d[lane + j * 64] = src[lane + j * 64];
    } else {
        float4 v0 = src[lane * 4 + 0], v1 = src[lane * 4 + 1];
        float4 v2 = src[lane * 4 + 2], v3 = src[lane * 4 + 3];
        short8 h0, h1;
        h0[0]=f2bf(v0.x); h0[1]=f2bf(v0.y); h0[2]=f2bf(v0.z); h0[3]=f2bf(v0.w);
        h0[4]=f2bf(v1.x); h0[5]=f2bf(v1.y); h0[6]=f2bf(v1.z); h0[7]=f2bf(v1.w);
        h1[0]=f2bf(v2.x); h1[1]=f2bf(v2.y); h1[2]=f2bf(v2.z); h1[3]=f2bf(v2.w);
        h1[4]=f2bf(v3.x); h1[5]=f2bf(v3.y); h1[6]=f2bf(v3.z); h1[7]=f2bf(v3.w);
        unsigned short* d = Abf + (size_t)s * DDIM + lane * 16;
        *(short8*)d = h0;
        *(short8*)(d + 8) = h1;
    }
}

// One K-tile (R9 order + counted vmcnt): reads1 -> issue A(t+1),B(t+2) ->
// MFMA1 -> reads2 -> MFMA2 -> vmcnt(VMN) -> barrier.  VMN=4 leaves B(t+2)
// in flight across the barrier; next tile's buffers are already resident.
#define TILEX(AR, BR, sNA, sNB, KT, VMN)                           \
    do {                                                           \
        short8 a1[8], b1[4];                                       \
        _Pragma("unroll")                                          \
        for (int m = 0; m < 8; ++m)                                \
            a1[m] = *(const short8*)(AR + sl0 + m * 2048);         \
        _Pragma("unroll")                                          \
        for (int n = 0; n < 4; ++n)                                \
            b1[n] = *(const short8*)(BR + sl0 + n * 2048);         \
        if ((KT) + 1 < NKT) {                                      \
            _Pragma("unroll")                                      \
            for (int q = 0; q < 4; ++q)                            \
                gload16(aSrc[q] + ((KT) + 1) * BK, sNA + q * 8192);\
        }                                                          \
        if ((KT) + 2 < NKT) {                                      \
            _Pragma("unroll")                                      \
            for (int q = 0; q < 4; ++q)                            \
                gload16(bSrc[q] + ((KT) + 2) * BK, sNB + q * 8192);\
        }                                                          \
        __builtin_amdgcn_s_setprio(1);                             \
        _Pragma("unroll")                                          \
        for (int m = 0; m < 8; ++m)                                \
            _Pragma("unroll")                                      \
            for (int n = 0; n < 4; ++n)                            \
                acc[m][n] = __builtin_amdgcn_mfma_f32_16x16x32_bf16(\
                    a1[m], b1[n], acc[m][n], 0, 0, 0);             \
        __builtin_amdgcn_s_setprio(0);                             \
        short8 a2[8], b2[4];                                       \
        _Pragma("unroll")                                          \
        for (int m = 0; m < 8; ++m)                                \
            a2[m] = *(const short8*)(AR + sl1 + m * 2048);         \
        _Pragma("unroll")                                          \
        for (int n = 0; n < 4; ++n)                                \
            b2[n] = *(const short8*)(BR + sl1 + n * 2048);         \
        __builtin_amdgcn_s_setprio(1);                             \
        _Pragma("unroll")                                          \
        for (int m = 0; m < 8; ++m)                                \
            _Pragma("unroll")                                      \
            for (int n = 0; n < 4; ++n)                            \
                acc[m][n] = __builtin_amdgcn_mfma_f32_16x16x32_bf16(\
                    a2[m], b2[n], acc[m][n], 0, 0, 0);             \
        __builtin_amdgcn_s_setprio(0);                             \
        asm volatile("s_waitcnt vmcnt(" #VMN ")" ::: "memory");    \
        __builtin_amdgcn_s_barrier();                              \
    } while (0)

__global__ __launch_bounds__(512, 2) void gemm_k(
    const unsigned short* __restrict__ Abf,
    const unsigned short* __restrict__ Wbf,
    const float* __restrict__ bias, float* __restrict__ out,
    const int* __restrict__ wsi) {
    const int bid = blockIdx.x;              // 0..255, 1 per CU
    const int c = bid & 7;                   // XCD
    const int g = bid >> 3;
    const int ntiles = wsi[WI_NTILES];
    const int* offs = wsi + WI_OFFS;
    const int* tab  = wsi + WI_TABLE;
    const int* ctok = wsi + WI_CTOK;

    // 160 KB exactly: A dbuf + B tribuf, all distinct (compile-time rotation).
    __shared__ unsigned short As0[BM * BK];   // 32 KB each
    __shared__ unsigned short As1[BM * BK];
    __shared__ unsigned short Bs0[BM * BK];
    __shared__ unsigned short Bs1[BM * BK];
    __shared__ unsigned short Bs2[BM * BK];

    const int tid = threadIdx.x, lane = tid & 63, wave = tid >> 6;
    const int wr = wave >> 2, wc = wave & 3;     // wave-tile 128x64
    const int lane15 = lane & 15;
    const int srow = lane >> 3;                          // 0..7
    const int schunk = ((lane & 7) ^ srow) * 8;          // inverse-swizzled src

    const int sl0 = (((lane >> 4)) ^ (lane & 7)) * 16;
    const int sl1 = ((4 | (lane >> 4)) ^ (lane & 7)) * 16;
    const char* aR0 = (const char*)As0 + wr * 16384 + lane15 * 128;
    const char* aR1 = (const char*)As1 + wr * 16384 + lane15 * 128;
    const char* bR0 = (const char*)Bs0 + wc * 8192 + lane15 * 128;
    const char* bR1 = (const char*)Bs1 + wc * 8192 + lane15 * 128;
    const char* bR2 = (const char*)Bs2 + wc * 8192 + lane15 * 128;
    char* sA0 = (char*)As0 + wave * 1024;
    char* sA1 = (char*)As1 + wave * 1024;
    char* sB0 = (char*)Bs0 + wave * 1024;
    char* sB1 = (char*)Bs1 + wave * 1024;
    char* sB2 = (char*)Bs2 + wave * 1024;

    for (int rep = 0; rep < 2; ++rep) {
        const int q4 = g + 32 * rep;
        const int ty = (q4 >> 2) * 8 + c;
        const int tx = q4 & 3;
        if (ty >= ntiles) break;

        const int e     = tab[2 * ty];
        const int crow0 = tab[2 * ty + 1];
        const int nend  = offs[e + 1];
        const int col0  = tx * BN;
        const unsigned short* Wb = Wbf + (size_t)e * DDIM * DDIM;

        const unsigned short* aSrc[4];
        const unsigned short* bSrc[4];
#pragma unroll
        for (int q = 0; q < 4; ++q) {
            int r = min(crow0 + q * 64 + wave * 8 + srow, NTOK - 1);
            aSrc[q] = Abf + (size_t)r * DDIM + schunk;
            bSrc[q] = Wb + (size_t)(col0 + q * 64 + wave * 8 + srow) * DDIM + schunk;
        }

        f32x4 acc[8][4];
#pragma unroll
        for (int m = 0; m < 8; ++m)
#pragma unroll
            for (int n = 0; n < 4; ++n) acc[m][n] = (f32x4){0.f, 0.f, 0.f, 0.f};

        // prologue: B0, A0, B1; vmcnt(4) -> B0+A0 resident, B1 in flight
#pragma unroll
        for (int q = 0; q < 4; ++q) gload16(bSrc[q], sB0 + q * 8192);
#pragma unroll
        for (int q = 0; q < 4; ++q) gload16(aSrc[q], sA0 + q * 8192);
#pragma unroll
        for (int q = 0; q < 4; ++q) gload16(bSrc[q] + BK, sB1 + q * 8192);
        asm volatile("s_waitcnt vmcnt(4)" ::: "memory");
        __builtin_amdgcn_s_barrier();

        // 16 tiles, A buf = t&1, B buf = t%3, issue A(t+1), B(t+2)
        TILEX(aR0, bR0, sA1, sB2,  0, 4);
        TILEX(aR1, bR1, sA0, sB0,  1, 4);
        TILEX(aR0, bR2, sA1, sB1,  2, 4);
        TILEX(aR1, bR0, sA0, sB2,  3, 4);
        TILEX(aR0, bR1, sA1, sB0,  4, 4);
        TILEX(aR1, bR2, sA0, sB1,  5, 4);
        TILEX(aR0, bR0, sA1, sB2,  6, 4);
        TILEX(aR1, bR1, sA0, sB0,  7, 4);
        TILEX(aR0, bR2, sA1, sB1,  8, 4);
        TILEX(aR1, bR0, sA0, sB2,  9, 4);
        TILEX(aR0, bR1, sA1, sB0, 10, 4);
        TILEX(aR1, bR2, sA0, sB1, 11, 4);
        TILEX(aR0, bR0, sA1, sB2, 12, 4);
        TILEX(aR1, bR1, sA0, sB0, 13, 4);
        TILEX(aR0, bR2, sA1, sB1, 14, 0);
        TILEX(aR1, bR0, sA0, sB2, 15, 0);

        // epilogue: bias + gathered store (C/D: col=lane&15, row=(lane>>4)*4+r)
        const int crow4 = (lane >> 4) * 4;
        float bv[4];
#pragma unroll
        for (int n = 0; n < 4; ++n)
            bv[n] = bias[e * DDIM + col0 + wc * 64 + n * 16 + lane15];

#pragma unroll
        for (int m = 0; m < 8; ++m) {
#pragma unroll
            for (int r = 0; r < 4; ++r) {
                int gr = crow0 + wr * 128 + m * 16 + crow4 + r;
                if (gr >= nend) continue;
                int tok = ctok[gr];
                float* orow = out + (size_t)tok * DDIM + col0 + wc * 64 + lane15;
#pragma unroll
                for (int n = 0; n < 4; ++n)
                    orow[n * 16] = acc[m][n][r] + bv[n];
            }
        }
        __builtin_amdgcn_s_barrier();   // LDS quiesced before next rep's stage
    }
}

extern "C" void kernel_launch(void* const* d_in, const int* in_sizes, int n_in,
                              void* d_out, int out_size, void* d_ws, size_t ws_size,
                              hipStream_t stream) {
    const float* actions = (const float*)d_in[0];
    const int*   atype   = (const int*)d_in[1];
    const float* W       = (const float*)d_in[2];
    const float* bias    = (const float*)d_in[3];
    float* out = (float*)d_out;

    int* wsi = (int*)d_ws;
    unsigned short* Abf = (unsigned short*)((char*)d_ws + WS_ABF_B);
    unsigned short* Wbf = (unsigned short*)((char*)d_ws + WS_WBF_B);

    routeconv_k<<<1 + 1792, 256, 0, stream>>>(atype, wsi, W, Wbf);
    aconv_k<<<NTOK / 4, 256, 0, stream>>>(actions, wsi, Abf, out);
    gemm_k<<<256, 512, 0, stream>>>(Abf, Wbf, bias, out, wsi);
}